// Round 2
// baseline (1996.305 us; speedup 1.0000x reference)
//
#include <hip/hip_runtime.h>
#include <hip/hip_bf16.h>
#include <stdint.h>

// Problem constants (fixed by setup_inputs)
#define NN 16384
#define DD 512
#define NSTRIPE 8     // column stripes, one per XCD (blockIdx % 8)
#define SCOLS 2048    // NN / NSTRIPE
#define BM 128        // block row tile
#define BN 128        // block col tile
#define BK 64         // k chunk staged in LDS
#define SK 72         // padded LDS k-stride in bf16 elems (64 + 8 -> conflict-free ds_read_b128)
#define NTILES 16     // SCOLS / BN
#define NEG_INF (-3.0e38f)

typedef unsigned short u16;
typedef __attribute__((ext_vector_type(8))) __bf16 bf16x8;  // MFMA A/B operand (4 VGPRs)
typedef __attribute__((ext_vector_type(8))) short sh8;      // 16B staging vector
typedef __attribute__((ext_vector_type(4))) float f32x4;    // MFMA C/D

__device__ __forceinline__ u16 f2bf(float f) {  // RNE fp32->bf16
  uint32_t x = __float_as_uint(f);
  x += 0x7fffu + ((x >> 16) & 1u);
  return (u16)(x >> 16);
}
__device__ __forceinline__ float bf2f(u16 u) {
  return __uint_as_float(((uint32_t)u) << 16);
}

// Insert v into descending-sorted 10-element register array.
__device__ __forceinline__ void ins10(float t[10], float v) {
  #pragma unroll
  for (int j = 0; j < 10; ++j) {
    float hi = fmaxf(t[j], v);
    v = fminf(t[j], v);
    t[j] = hi;
  }
}

__global__ __launch_bounds__(256) void cast_kernel(const float* __restrict__ src,
                                                   u16* __restrict__ dst) {
  int i = (blockIdx.x * 256 + threadIdx.x) * 8;
  const float4* s4 = reinterpret_cast<const float4*>(src + i);
  float4 a = s4[0], b = s4[1];
  sh8 o;
  o[0] = (short)f2bf(a.x); o[1] = (short)f2bf(a.y);
  o[2] = (short)f2bf(a.z); o[3] = (short)f2bf(a.w);
  o[4] = (short)f2bf(b.x); o[5] = (short)f2bf(b.y);
  o[6] = (short)f2bf(b.z); o[7] = (short)f2bf(b.w);
  *reinterpret_cast<sh8*>(dst + i) = o;
}

// diag[r] = <Lb_r, Rb_r> (bf16 inputs, fp32 accumulate) — one wave per row
__global__ __launch_bounds__(256) void diag_kernel(const u16* __restrict__ Lb,
                                                   const u16* __restrict__ Rb,
                                                   float* __restrict__ diag) {
  int r = blockIdx.x * 4 + (threadIdx.x >> 6);
  int lane = threadIdx.x & 63;
  sh8 a = *reinterpret_cast<const sh8*>(Lb + (size_t)r * DD + lane * 8);
  sh8 b = *reinterpret_cast<const sh8*>(Rb + (size_t)r * DD + lane * 8);
  float s = 0.f;
  #pragma unroll
  for (int j = 0; j < 8; ++j) s += bf2f((u16)a[j]) * bf2f((u16)b[j]);
  #pragma unroll
  for (int off = 32; off > 0; off >>= 1) s += __shfl_down(s, off);
  if (lane == 0) diag[r] = s;
}

// Fused GEMM + consumer. Computes rows [rowbase,rowbase+128) x stripe cols of A*B^T
// (A,B are [NN][DD] bf16 row-major; cols of the product are rows of B).
// MODE 0: per-row top-10 within the stripe -> part_out[N][8][10]
// MODE 1: per-row count(2v - p[col] > thr[row]) and max(2v - p[col]) -> cnt/mx parts
template <int MODE>
__global__ __launch_bounds__(256) void csls_gemm(
    const u16* __restrict__ A, const u16* __restrict__ B,
    float* __restrict__ part_out,
    const float* __restrict__ p, const float* __restrict__ thr,
    int* __restrict__ cnt_out, float* __restrict__ mx_out) {
  __shared__ u16 smem[2 * BM * SK];  // 36864 B: sA | sB; aliased as fp32 C-buffer in MODE 0
  u16* sA = smem;
  u16* sB = smem + BM * SK;

  const int stripe = blockIdx.x & 7;        // XCD-aligned stripe
  const int rowtile = blockIdx.x >> 3;
  const int rowbase = rowtile * BM;
  const int sbase = stripe * SCOLS;

  const int tid = threadIdx.x;
  const int w = tid >> 6;
  const int lane = tid & 63;
  const int quad = lane >> 4;
  const int l16 = lane & 15;
  const int wr = (w >> 1) * 64;  // wave quadrant rows
  const int wc = (w & 1) * 64;   // wave quadrant cols

  float tk[2][10];   // MODE 0: running top-10, phase 0 = row tid>>2, phase 1 = 64 + tid>>2
  int cnt[16];       // MODE 1 state: per (fr,reg) row this lane holds
  float mx[16];
  float thrv[16];
  if constexpr (MODE == 0) {
    #pragma unroll
    for (int ph = 0; ph < 2; ++ph)
      #pragma unroll
      for (int j = 0; j < 10; ++j) tk[ph][j] = NEG_INF;
  } else {
    #pragma unroll
    for (int i = 0; i < 16; ++i) {
      cnt[i] = 0;
      mx[i] = NEG_INF;
      int fr = i >> 2, reg = i & 3;
      thrv[i] = thr[rowbase + wr + 16 * fr + quad * 4 + reg];
    }
  }

  for (int tile = 0; tile < NTILES; ++tile) {
    const int colbase = sbase + tile * BN;
    f32x4 acc[4][4];
    #pragma unroll
    for (int a_ = 0; a_ < 4; ++a_)
      #pragma unroll
      for (int b_ = 0; b_ < 4; ++b_) acc[a_][b_] = (f32x4){0.f, 0.f, 0.f, 0.f};

    float pv[4];
    if constexpr (MODE == 1) {  // prefetch p for this tile's 4 column fragments
      #pragma unroll
      for (int fc = 0; fc < 4; ++fc) pv[fc] = p[colbase + wc + 16 * fc + l16];
    }

    for (int kk = 0; kk < DD; kk += BK) {
      // stage A chunk [128 rows][64 k] and B chunk [128 cols][64 k], padded stride
      #pragma unroll
      for (int it = 0; it < 4; ++it) {
        int gid = it * 256 + tid;       // 0..1023 16B-granules
        int row = gid >> 3, g = gid & 7;
        sh8 va = *reinterpret_cast<const sh8*>(A + (size_t)(rowbase + row) * DD + kk + g * 8);
        sh8 vb = *reinterpret_cast<const sh8*>(B + (size_t)(colbase + row) * DD + kk + g * 8);
        *reinterpret_cast<sh8*>(sA + row * SK + g * 8) = va;
        *reinterpret_cast<sh8*>(sB + row * SK + g * 8) = vb;
      }
      __syncthreads();
      #pragma unroll
      for (int ks = 0; ks < BK; ks += 32) {
        bf16x8 af[4], bfr[4];
        #pragma unroll
        for (int f = 0; f < 4; ++f) {
          af[f]  = *reinterpret_cast<const bf16x8*>(sA + (wr + 16 * f + l16) * SK + ks + quad * 8);
          bfr[f] = *reinterpret_cast<const bf16x8*>(sB + (wc + 16 * f + l16) * SK + ks + quad * 8);
        }
        #pragma unroll
        for (int fr = 0; fr < 4; ++fr)
          #pragma unroll
          for (int fc = 0; fc < 4; ++fc)
            acc[fr][fc] = __builtin_amdgcn_mfma_f32_16x16x32_bf16(af[fr], bfr[fc], acc[fr][fc], 0, 0, 0);
      }
      __syncthreads();
    }

    if constexpr (MODE == 0) {
      // Dump C in two 64-row phases into LDS (reusing staging space), scan 4 thr/row.
      float* sC = reinterpret_cast<float*>(smem);  // [64][129] = 33 KB <= 36 KB
      #pragma unroll
      for (int ph = 0; ph < 2; ++ph) {
        if ((w >> 1) == ph) {
          #pragma unroll
          for (int fr = 0; fr < 4; ++fr)
            #pragma unroll
            for (int fc = 0; fc < 4; ++fc)
              #pragma unroll
              for (int reg = 0; reg < 4; ++reg)
                sC[(16 * fr + quad * 4 + reg) * 129 + wc + 16 * fc + l16] = acc[fr][fc][reg];
        }
        __syncthreads();
        {
          const int rloc = tid >> 2;
          const int cb = tid & 3;   // interleaved cols: bank-conflict-free
          #pragma unroll 4
          for (int i = 0; i < 32; ++i) {
            float v = sC[rloc * 129 + cb + 4 * i];
            if (v > tk[ph][9]) ins10(tk[ph], v);
          }
        }
        __syncthreads();
      }
    } else {
      // Register-direct consume: csls = 2*v - p[col]; count > thr[row]; track max.
      #pragma unroll
      for (int fc = 0; fc < 4; ++fc)
        #pragma unroll
        for (int fr = 0; fr < 4; ++fr)
          #pragma unroll
          for (int reg = 0; reg < 4; ++reg) {
            float t = 2.f * acc[fr][fc][reg] - pv[fc];
            int idx = fr * 4 + reg;
            cnt[idx] += (t > thrv[idx]) ? 1 : 0;
            mx[idx] = fmaxf(mx[idx], t);
          }
    }
  }

  if constexpr (MODE == 0) {
    // Merge 4 partial top-10s per row, write stripe top-10.
    float* sM = reinterpret_cast<float*>(smem);  // [64][40]
    #pragma unroll
    for (int ph = 0; ph < 2; ++ph) {
      __syncthreads();
      #pragma unroll
      for (int j = 0; j < 10; ++j)
        sM[(tid >> 2) * 40 + (tid & 3) * 10 + j] = tk[ph][j];
      __syncthreads();
      if ((tid & 3) == 0) {
        float best[10];
        #pragma unroll
        for (int j = 0; j < 10; ++j) best[j] = NEG_INF;
        for (int j = 0; j < 40; ++j) {
          float v = sM[(tid >> 2) * 40 + j];
          if (v > best[9]) ins10(best, v);
        }
        int rowg = rowbase + ph * 64 + (tid >> 2);
        #pragma unroll
        for (int j = 0; j < 10; ++j)
          part_out[(size_t)rowg * 80 + stripe * 10 + j] = best[j];
      }
      __syncthreads();
    }
  } else {
    // RACE FIX (R1): rows are covered by TWO waves (w and w|1 share rows, each
    // holding a 64-column half). Reduce within each wave's 16 column-lanes,
    // deposit per-wave partials in LDS, then combine the wave pair per row.
    float* sMx = reinterpret_cast<float*>(smem);        // [4][64] floats
    int*   sCn = reinterpret_cast<int*>(smem) + 256;    // [4][64] ints
    #pragma unroll
    for (int idx = 0; idx < 16; ++idx) {
      int c = cnt[idx];
      float m = mx[idx];
      #pragma unroll
      for (int off = 1; off < 16; off <<= 1) {
        c += __shfl_xor(c, off);
        m = fmaxf(m, __shfl_xor(m, off));
      }
      if (l16 == 0) {
        int fr = idx >> 2, reg = idx & 3;
        int rloc = 16 * fr + quad * 4 + reg;   // row within this wave's 64-row half
        sMx[w * 64 + rloc] = m;
        sCn[w * 64 + rloc] = c;
      }
    }
    __syncthreads();
    if (tid < 128) {
      int half = tid >> 6;       // 0: rows 0-63 (waves 0,1); 1: rows 64-127 (waves 2,3)
      int rloc = tid & 63;
      int c = sCn[(half * 2) * 64 + rloc] + sCn[(half * 2 + 1) * 64 + rloc];
      float m = fmaxf(sMx[(half * 2) * 64 + rloc], sMx[(half * 2 + 1) * 64 + rloc]);
      cnt_out[(rowbase + tid) * 8 + stripe] = c;
      mx_out[(rowbase + tid) * 8 + stripe] = m;
    }
  }
}

// Merge 8 stripes x top-10 -> LR/RL means; p = LR+RL; thr = 2*diag - p
__global__ __launch_bounds__(256) void p_kernel(const float* __restrict__ LRp,
                                                const float* __restrict__ RLp,
                                                const float* __restrict__ diag,
                                                float* __restrict__ pout,
                                                float* __restrict__ throut) {
  int l = blockIdx.x * 256 + threadIdx.x;
  float b1[10], b2[10];
  #pragma unroll
  for (int j = 0; j < 10; ++j) { b1[j] = NEG_INF; b2[j] = NEG_INF; }
  for (int j = 0; j < 80; ++j) {
    float v = LRp[(size_t)l * 80 + j];
    if (v > b1[9]) ins10(b1, v);
    float u = RLp[(size_t)l * 80 + j];
    if (u > b2[9]) ins10(b2, u);
  }
  float s1 = 0.f, s2 = 0.f;
  #pragma unroll
  for (int j = 0; j < 10; ++j) { s1 += b1[j]; s2 += b2[j]; }
  float pv = (s1 + s2) * 0.1f;
  pout[l] = pv;
  throut[l] = 2.f * diag[l] - pv;
}

__global__ __launch_bounds__(256) void final_kernel(const int* __restrict__ cnt,
                                                    const float* __restrict__ mx,
                                                    float* __restrict__ out) {
  int r = blockIdx.x * 256 + threadIdx.x;
  int c = 0;
  float m = NEG_INF;
  #pragma unroll
  for (int s = 0; s < 8; ++s) {
    c += cnt[r * 8 + s];
    m = fmaxf(m, mx[r * 8 + s]);
  }
  out[r] = (float)c;   // rank of the diagonal element (count strictly greater)
  out[NN + r] = m;     // top-1 csls value
}

extern "C" void kernel_launch(void* const* d_in, const int* in_sizes, int n_in,
                              void* d_out, int out_size, void* d_ws, size_t ws_size,
                              hipStream_t stream) {
  const float* L = (const float*)d_in[0];
  const float* R = (const float*)d_in[1];
  char* ws = (char*)d_ws;

  u16* Lb = (u16*)ws;                                  // 16 MB
  u16* Rb = (u16*)(ws + (16ull << 20));                // 16 MB
  size_t off = 32ull << 20;
  float* LRpart = (float*)(ws + off); off += (size_t)NN * 80 * 4;  // 5.24 MB
  float* RLpart = (float*)(ws + off); off += (size_t)NN * 80 * 4;  // 5.24 MB
  float* diag   = (float*)(ws + off); off += (size_t)NN * 4;
  float* pbuf   = (float*)(ws + off); off += (size_t)NN * 4;
  float* thrbuf = (float*)(ws + off); off += (size_t)NN * 4;
  int*   cntp   = (int*)(ws + off);   off += (size_t)NN * 8 * 4;
  float* mxp    = (float*)(ws + off); off += (size_t)NN * 8 * 4;   // total ~43.7 MB

  // 1) fp32 -> bf16 casts
  cast_kernel<<<(NN * DD / (256 * 8)), 256, 0, stream>>>(L, Lb);
  cast_kernel<<<(NN * DD / (256 * 8)), 256, 0, stream>>>(R, Rb);
  // 2) diagonal sim values
  diag_kernel<<<NN / 4, 256, 0, stream>>>(Lb, Rb, diag);
  // 3) LR[l] parts: rows of L*R^T
  csls_gemm<0><<<(NN / BM) * NSTRIPE, 256, 0, stream>>>(Lb, Rb, LRpart, nullptr, nullptr, nullptr, nullptr);
  // 4) RL[r] parts: rows of R*L^T
  csls_gemm<0><<<(NN / BM) * NSTRIPE, 256, 0, stream>>>(Rb, Lb, RLpart, nullptr, nullptr, nullptr, nullptr);
  // 5) merge partials -> p, thr
  p_kernel<<<NN / 256, 256, 0, stream>>>(LRpart, RLpart, diag, pbuf, thrbuf);
  // 6) rank + max pass over rows of R*L^T
  csls_gemm<1><<<(NN / BM) * NSTRIPE, 256, 0, stream>>>(Rb, Lb, nullptr, pbuf, thrbuf, cntp, mxp);
  // 7) reduce stripe parts -> outputs
  final_kernel<<<NN / 256, 256, 0, stream>>>(cntp, mxp, (float*)d_out);
}